// Round 13
// baseline (297.378 us; speedup 1.0000x reference)
//
#include <hip/hip_runtime.h>

typedef _Float16 f16;
typedef _Float16 f16x8 __attribute__((ext_vector_type(8)));
typedef _Float16 f16x4 __attribute__((ext_vector_type(4)));
typedef float f32x4 __attribute__((ext_vector_type(4)));

#define MFMA16(a, b, c) __builtin_amdgcn_mfma_f32_16x16x32_f16((a), (b), (c), 0, 0, 0)

#define BATCH 32768

// workspace layout (bytes)
#define OFF_GATESA  ((size_t)0)                    // gatesA: B*128 f16 = 8,388,608 (dec_in only)
#define OFF_BF      (OFF_GATESA + 8388608)         // Bf3 [8][17][64][8] f16 = 139,264
#define OFF_W1      (OFF_BF + 139264)              // W1i [13][128][32] f16 = 106,496
#define OFF_W2      (OFF_W1 + 106496)              // [64][384]
#define OFF_W3      (OFF_W2 + 49152)               // [64][192]
#define OFF_W4      (OFF_W3 + 24576)               // [128][64]
#define OFF_WG      (OFF_W4 + 16384)               // [512][256]

__device__ __forceinline__ float sigmoid_(float x) { return 1.f / (1.f + __expf(-x)); }

// ---------------------------------------------------------------------------
// prep: weight repacks only. Grid 256 (R12).
// ---------------------------------------------------------------------------
__global__ __launch_bounds__(256) void prep_kernel(
    const float* __restrict__ basis, const float* __restrict__ w1,
    const float* __restrict__ w2, const float* __restrict__ w3,
    const float* __restrict__ w4, const float* __restrict__ w_ih,
    const float* __restrict__ w_hh, f16* __restrict__ Bf3,
    f16* __restrict__ W1i, f16* __restrict__ W2, f16* __restrict__ W3,
    f16* __restrict__ W4, f16* __restrict__ Wg) {
  int t = blockIdx.x * 256 + threadIdx.x;  // 0..65535
  // basis -> Bf3 frag-major [kb][tile][lane][8]
  for (int idx = t; idx < 8 * 17 * 512; idx += 65536) {
    int jj = idx & 7;
    int lane = (idx >> 3) & 63;
    int rest = idx >> 9;
    int tt = rest % 17, kb = rest / 17;
    int n = tt * 16 + (lane & 15);
    int k = kb * 32 + (lane >> 4) * 8 + jj;
    Bf3[idx] = (f16)((n < 258) ? basis[n * 256 + k] : 0.f);
  }
  // w1 (128,129,3) -> W1i[kb][n][kk], logical k = tap*136 + i, K=416
  for (int idx = t; idx < 13 * 128 * 32; idx += 65536) {
    int kb = idx / 4096, rest = idx - kb * 4096;
    int n = rest >> 5, kk = rest & 31;
    int k = kb * 32 + kk;
    int tap = k / 136, i = k - tap * 136;
    float v = (tap < 3 && i < 129) ? w1[(n * 129 + i) * 3 + tap] : 0.f;
    W1i[idx] = (f16)v;
  }
  // w2 (64,128,3) -> W2[n][k], k = tap*128 + i, K=384
  for (int idx = t; idx < 64 * 384; idx += 65536) {
    int n = idx / 384, k = idx - n * 384;
    int tap = k >> 7, i = k & 127;
    W2[idx] = (f16)w2[(n * 128 + i) * 3 + tap];
  }
  // w3 (64,64,3) -> W3[n][k], k = tap*64 + i, K=192
  for (int idx = t; idx < 64 * 192; idx += 65536) {
    int n = idx / 192, k = idx - n * 192;
    int tap = k >> 6, i = k & 63;
    W3[idx] = (f16)w3[(n * 64 + i) * 3 + tap];
  }
  // w4 (128,64,3), only tap=1 contributes -> W4[n][i], K=64
  for (int idx = t; idx < 128 * 64; idx += 65536) {
    int n = idx >> 6, i = idx & 63;
    W4[idx] = (f16)w4[(n * 64 + i) * 3 + 1];
  }
  // Wg[512][256] = [w_ih | w_hh]
  for (int idx = t; idx < 512 * 256; idx += 65536) {
    int n = idx >> 8, k = idx & 255;
    Wg[idx] = (f16)((k < 128) ? w_ih[n * 128 + k] : w_hh[n * 128 + (k - 128)]);
  }
}

// ---------------------------------------------------------------------------
// fused: R11 structure (1024 thr / 16 waves, depth-2 pipelined, 82% occ)
// + R13: LDS bank-conflict fix (T2-style). Old strides were all == 4 dwords
// mod 32 (XP 356dw, MG 420dw, E1 324dw, E2 100dw) -> every MFMA A-read
// ds_read_b128 hit bank 4*(l15+quad) mod 32 -> 6.9M conflict cycles/dispatch
// (~25-30% LDS-pipe overhead on the MFMA critical path). Fix: row strides
// padded to multiples of 64 f16 (bank-aligned: XP 768, MG 896, E1 640,
// E2 256, E3 64) + XOR the 16B-granule index with (row&7) on BOTH writes
// and reads (same involution). All vector accesses remain granule-aligned;
// all read sets are subsets of written/zeroed sets (mag's last partial
// window lives in the 896 pad). LDS 55,552 B -> still 2 blocks/CU (the
// 32-wave cap limits to 2 anyway).
// ---------------------------------------------------------------------------
__global__ __launch_bounds__(1024, 8) void fused_kernel(
    const float* __restrict__ x, const f16* __restrict__ Bf3,
    const f16* __restrict__ W1i, const float* __restrict__ b1,
    const f16* __restrict__ W2, const float* __restrict__ b2,
    const f16* __restrict__ W3, const float* __restrict__ b3,
    const f16* __restrict__ W4, const float* __restrict__ b4,
    f16* __restrict__ gatesA) {
  __shared__ __align__(16) char smem[55552];
  f16* SF = (f16*)smem;
  float* imPatch = (float*)(smem + 53248);  // f32[9][64], dedicated
#define SWZ(row, j) ((j) ^ (((row) & 7) << 3))
#define XP(bl, j) ((bl)*768 + SWZ(bl, j))
#define E1(bl, s, c) ((bl)*640 + SWZ(bl, (s)*128 + (c)))
#define E3(bl, c) ((bl)*64 + SWZ(bl, c))
#define MG(bl, j) (12288 + (bl)*896 + SWZ(bl, j))
#define E2(bl, s, c) (12288 + (bl)*256 + SWZ(bl, (s)*64 + (c)))

  int tid = threadIdx.x;
  int lane = tid & 63, wv = tid >> 6;  // wv in 0..15
  int l15 = lane & 15, quad = lane >> 4;
  int b0 = blockIdx.x * 16;
  f32x4 zero4 = {0.f, 0.f, 0.f, 0.f};

  // ---- phase 0: build xpL[0,640); zero ALL of magL (stale LDS there is
  //      multiplied by zero weights — must not be Inf/NaN). ----
  for (int idx = tid; idx < 16 * 160; idx += 1024) {
    int bl = idx / 160, g = idx - bl * 160;
    int b = b0 + bl;
    f16x4 o;
    if (g < 32) {
      float v0 = (g == 0) ? x[(size_t)b * 512] : 0.f;
      o = (f16x4){(f16)v0, (f16)0.f, (f16)0.f, (f16)0.f};
    } else {
      const float4 v = *(const float4*)(x + (size_t)b * 512 + 4 * g - 128);
      o = (f16x4){(f16)v.x, (f16)v.y, (f16)v.z, (f16)v.w};
    }
    *(f16x4*)&SF[XP(bl, 4 * g)] = o;
  }
  {
    f16x8 z8 = {};
    for (int idx = tid; idx < 16 * 105; idx += 1024) {  // magL used window
      int bl = idx / 105, g = idx - bl * 105;
      *(f16x8*)&SF[MG(bl, g * 8)] = z8;
    }
  }
  __syncthreads();

  // ---- STFT: wave (tp, mh): re-tile tp, im-tile tp+8, frames 2mh, 2mh+1. ----
  {
    int tp = wv & 7, mh = wv >> 3;
    const f16* Bl = Bf3 + lane * 8;
    int m0 = mh * 2, m1 = mh * 2 + 1;

    // tile16 pre-pass on waves 0 (frames 0,1) and 8 (frames 2,3).
    if (tp == 0) {
      f32x4 acc4[2] = {zero4, zero4};
      for (int kb = 0; kb < 8; kb++) {
        f16x8 bc4 = *(const f16x8*)(Bl + (size_t)kb * 17 * 512 + 16 * 512);
#pragma unroll
        for (int m = 0; m < 2; m++) {
          int mt = mh * 2 + m;
          f16x8 a = *(const f16x8*)&SF[XP(l15, mt * 128 + kb * 32 + quad * 8)];
          acc4[m] = MFMA16(a, bc4, acc4[m]);
        }
      }
      if (l15 < 2) {
        float* dst = imPatch + (l15 == 0 ? 7 : 8) * 64;
#pragma unroll
        for (int m = 0; m < 2; m++)
#pragma unroll
          for (int r = 0; r < 4; r++)
            dst[(mh * 2 + m) * 16 + quad * 4 + r] = acc4[m][r];
      }
    }

    f32x4 acc0[2], acc1v[2];
#pragma unroll
    for (int m = 0; m < 2; m++) {
      acc0[m] = zero4;
      acc1v[m] = zero4;
    }

    // depth-2 pipelined main loop.
    f16x8 a0 = *(const f16x8*)&SF[XP(l15, m0 * 128 + quad * 8)];
    f16x8 a1 = *(const f16x8*)&SF[XP(l15, m1 * 128 + quad * 8)];
    f16x8 b0 = *(const f16x8*)(Bl + tp * 512);
    f16x8 b1 = *(const f16x8*)(Bl + (tp + 8) * 512);
    for (int kb = 0; kb < 8; kb++) {
      f16x8 na0, na1, nb0, nb1;
      if (kb < 7) {
        const f16* Bn = Bl + (size_t)(kb + 1) * 17 * 512;
        nb0 = *(const f16x8*)(Bn + tp * 512);
        nb1 = *(const f16x8*)(Bn + (tp + 8) * 512);
        na0 = *(const f16x8*)&SF[XP(l15, m0 * 128 + (kb + 1) * 32 + quad * 8)];
        na1 = *(const f16x8*)&SF[XP(l15, m1 * 128 + (kb + 1) * 32 + quad * 8)];
      }
      acc0[0] = MFMA16(a0, b0, acc0[0]);
      acc1v[0] = MFMA16(a0, b1, acc1v[0]);
      acc0[1] = MFMA16(a1, b0, acc0[1]);
      acc1v[1] = MFMA16(a1, b1, acc1v[1]);
      if (kb < 7) { a0 = na0; a1 = na1; b0 = nb0; b1 = nb1; }
    }

    // Publish boundary columns.
    if (tp >= 1 && l15 == 0) {
#pragma unroll
      for (int m = 0; m < 2; m++)
#pragma unroll
        for (int r = 0; r < 4; r++)
          imPatch[(tp - 1) * 64 + (mh * 2 + m) * 16 + quad * 4 + r] =
              acc1v[m][r];
    }
    __syncthreads();

#pragma unroll
    for (int m = 0; m < 2; m++)
#pragma unroll
      for (int r = 0; r < 4; r++) {
        int mt = mh * 2 + m;
        int bl = quad * 4 + r;  // batch
        int jb = (mt + 1) * 136;
        int row = mt * 16 + quad * 4 + r;
        {
          float re = acc0[m][r];
          float imA = __shfl(acc1v[m][r], (quad << 4) | ((l15 + 1) & 15), 64);
          float im = (l15 == 15) ? imPatch[tp * 64 + row] : imA;
          SF[MG(bl, jb + 16 * tp + l15)] = (f16)sqrtf(re * re + im * im);
        }
        if (tp == 0 && l15 == 0) {
          float re8 = acc1v[m][r];
          float im8 = imPatch[8 * 64 + row];
          SF[MG(bl, jb + 128)] = (f16)sqrtf(re8 * re8 + im8 * im8);
        }
      }
  }
  __syncthreads();

  // ---- conv1: wave (nt=wv&7, ph=wv>>3), depth-2 pipelined. ----
  {
    f16x8 z8 = {};
    for (int idx = tid; idx < 16 * 16; idx += 1024) {
      int bl = idx >> 4, g = idx & 15;
      *(f16x8*)&SF[E1(bl, 0, g * 8)] = z8;  // zero e1 slot0
    }
    int nt = wv & 7, ph = wv >> 3;
    int p0 = ph * 2, p1 = ph * 2 + 1;
    f32x4 acc1[2] = {zero4, zero4};
    const f16* bbase = W1i + (nt * 16 + l15) * 32 + quad * 8;
    f16x8 b = *(const f16x8*)(bbase);
    f16x8 a0 = *(const f16x8*)&SF[MG(l15, p0 * 136 + quad * 8)];
    f16x8 a1 = *(const f16x8*)&SF[MG(l15, p1 * 136 + quad * 8)];
    for (int kb = 0; kb < 13; kb++) {
      f16x8 nb, na0, na1;
      if (kb < 12) {
        nb = *(const f16x8*)(bbase + (kb + 1) * 4096);
        na0 = *(const f16x8*)&SF[MG(l15, p0 * 136 + (kb + 1) * 32 + quad * 8)];
        na1 = *(const f16x8*)&SF[MG(l15, p1 * 136 + (kb + 1) * 32 + quad * 8)];
      }
      acc1[0] = MFMA16(a0, b, acc1[0]);
      acc1[1] = MFMA16(a1, b, acc1[1]);
      if (kb < 12) { a0 = na0; a1 = na1; b = nb; }
    }
    float bias = b1[nt * 16 + l15];
#pragma unroll
    for (int pi = 0; pi < 2; pi++)
#pragma unroll
      for (int r = 0; r < 4; r++) {
        int bl = quad * 4 + r;
        SF[E1(bl, ph * 2 + pi + 1, nt * 16 + l15)] =
            (f16)fmaxf(acc1[pi][r] + bias, 0.f);
      }
  }
  __syncthreads();

  // ---- conv2: waves 0-7, depth-2 pipelined. ----
  {
    {
      f16x8 z8 = {};
      for (int idx = tid; idx < 16 * 8; idx += 1024) {  // zero e2 slot0
        int bl = idx >> 3, g = idx & 7;
        *(f16x8*)&SF[E2(bl, 0, g * 8)] = z8;
      }
    }
    if (wv < 8) {
      int wr = wv & 1, wc = wv >> 1;
      f32x4 acc2 = zero4;
      const f16* bbase = W2 + (size_t)(wc * 16 + l15) * 384 + quad * 8;
      f16x8 b = *(const f16x8*)(bbase);
      f16x8 a = *(const f16x8*)&SF[E1(l15, wr * 2, quad * 8)];
      for (int kb = 0; kb < 12; kb++) {
        f16x8 nb, na;
        if (kb < 11) {
          nb = *(const f16x8*)(bbase + (kb + 1) * 32);
          na = *(const f16x8*)&SF[E1(l15, wr * 2, (kb + 1) * 32 + quad * 8)];
        }
        acc2 = MFMA16(a, b, acc2);
        if (kb < 11) { a = na; b = nb; }
      }
      float bias = b2[wc * 16 + l15];
#pragma unroll
      for (int r = 0; r < 4; r++) {
        int bl = quad * 4 + r;
        SF[E2(bl, wr + 1, wc * 16 + l15)] = (f16)fmaxf(acc2[r] + bias, 0.f);
      }
    }
  }
  __syncthreads();

  // ---- conv3: waves 0-3. ----
  if (wv < 4) {
    f32x4 acc3 = zero4;
    const f16* bbase = W3 + (size_t)(wv * 16 + l15) * 192 + quad * 8;
    for (int kb = 0; kb < 6; kb++) {
      f16x8 a = *(const f16x8*)&SF[E2(l15, 0, kb * 32 + quad * 8)];
      f16x8 bf = *(const f16x8*)(bbase + kb * 32);
      acc3 = MFMA16(a, bf, acc3);
    }
    float bias = b3[wv * 16 + l15];
#pragma unroll
    for (int r = 0; r < 4; r++) {
      int bl = quad * 4 + r;
      SF[E3(bl, wv * 16 + l15)] = (f16)fmaxf(acc3[r] + bias, 0.f);
    }
  }
  __syncthreads();

  // ---- conv4: waves 0-7 -> gatesA [B][128] ----
  if (wv < 8) {
    f32x4 acc4a = zero4;
    const f16* bbase = W4 + (size_t)(wv * 16 + l15) * 64 + quad * 8;
    for (int kb = 0; kb < 2; kb++) {
      f16x8 a = *(const f16x8*)&SF[E3(l15, kb * 32 + quad * 8)];
      f16x8 bf0 = *(const f16x8*)(bbase + kb * 32);
      acc4a = MFMA16(a, bf0, acc4a);
    }
    float bias = b4[wv * 16 + l15];
#pragma unroll
    for (int r = 0; r < 4; r++) {
      int bl = quad * 4 + r;
      gatesA[(size_t)(b0 + bl) * 128 + wv * 16 + l15] =
          (f16)fmaxf(acc4a[r] + bias, 0.f);
    }
  }
#undef SWZ
#undef XP
#undef MG
#undef E1
#undef E2
#undef E3
}

// ---------------------------------------------------------------------------
// gates GEMM + LSTM cell + decision head. M=128/block, 256 blocks, 1024
// threads / 16 waves (R12). A = [dec_in (f16) | h0 (f32 in-reg)], K=256.
// ---------------------------------------------------------------------------
__global__ __launch_bounds__(1024, 2) void gates_kernel(
    const f16* __restrict__ gatesA, const float* __restrict__ h0,
    const f16* __restrict__ Wg, const float* __restrict__ b_ih,
    const float* __restrict__ b_hh, const float* __restrict__ c0,
    const float* __restrict__ dec_w, const float* __restrict__ dec_b,
    float* __restrict__ out) {
  __shared__ float part[4][128];
  int tid = threadIdx.x;
  int lane = tid & 63, wv = tid >> 6;  // 0..15
  int wc = wv & 3;                     // col-group: cols wc*32 + u*16 + l15
  int wm = wv >> 2;                    // m-pair: mt = wm*2 + m, mt in 0..7
  int l15 = lane & 15, quad = lane >> 4;
  int b0 = blockIdx.x * 128;
  f32x4 zero4 = {0.f, 0.f, 0.f, 0.f};

  float* out_h1 = out + BATCH;
  float* out_c1 = out + BATCH + (size_t)BATCH * 128;

  f32x4 acc[2][8];  // [m][q*2+u]
#pragma unroll
  for (int m = 0; m < 2; m++)
#pragma unroll
    for (int j = 0; j < 8; j++) acc[m][j] = zero4;

  const f16* aptr[2];
  const float* hptr[2];
#pragma unroll
  for (int m = 0; m < 2; m++) {
    int mt = wm * 2 + m;
    aptr[m] = gatesA + (size_t)(b0 + mt * 16 + l15) * 128 + quad * 8;
    hptr[m] = h0 + (size_t)(b0 + mt * 16 + l15) * 128 + quad * 8;
  }

  const f16* bptrs[8];
#pragma unroll
  for (int q = 0; q < 4; q++)
#pragma unroll
    for (int u = 0; u < 2; u++)
      bptrs[q * 2 + u] =
          Wg + (size_t)(q * 128 + wc * 32 + u * 16 + l15) * 256 + quad * 8;

#pragma unroll
  for (int k0 = 0; k0 < 256; k0 += 32) {
    f16x8 a[2];
    if (k0 < 128) {
#pragma unroll
      for (int m = 0; m < 2; m++) a[m] = *(const f16x8*)(aptr[m] + k0);
    } else {
#pragma unroll
      for (int m = 0; m < 2; m++) {
        const float* hp = hptr[m] + (k0 - 128);
        float4 v0 = *(const float4*)hp;
        float4 v1 = *(const float4*)(hp + 4);
        a[m] = (f16x8){(f16)v0.x, (f16)v0.y, (f16)v0.z, (f16)v0.w,
                       (f16)v1.x, (f16)v1.y, (f16)v1.z, (f16)v1.w};
      }
    }
#pragma unroll
    for (int j = 0; j < 8; j++) {
      f16x8 bf = *(const f16x8*)(bptrs[j] + k0);
#pragma unroll
      for (int m = 0; m < 2; m++) acc[m][j] = MFMA16(a[m], bf, acc[m][j]);
    }
  }

  float bias[8], dw[2];
#pragma unroll
  for (int q = 0; q < 4; q++)
#pragma unroll
    for (int u = 0; u < 2; u++) {
      int n = q * 128 + wc * 32 + u * 16 + l15;
      bias[q * 2 + u] = b_ih[n] + b_hh[n];
    }
#pragma unroll
  for (int u = 0; u < 2; u++) dw[u] = dec_w[wc * 32 + u * 16 + l15];

#pragma unroll
  for (int m = 0; m < 2; m++)
#pragma unroll
    for (int r = 0; r < 4; r++) {
      int bl = (wm * 2 + m) * 16 + quad * 4 + r;
      int b = b0 + bl;
      float p = 0.f;
#pragma unroll
      for (int u = 0; u < 2; u++) {
        int c = wc * 32 + u * 16 + l15;
        float iv = acc[m][0 + u][r] + bias[0 + u];
        float fv = acc[m][2 + u][r] + bias[2 + u];
        float gv = acc[m][4 + u][r] + bias[4 + u];
        float ov = acc[m][6 + u][r] + bias[6 + u];
        float c0v = c0[(size_t)b * 128 + c];
        float c1 = sigmoid_(fv) * c0v + sigmoid_(iv) * tanhf(gv);
        float h1 = sigmoid_(ov) * tanhf(c1);
        out_h1[(size_t)b * 128 + c] = h1;
        out_c1[(size_t)b * 128 + c] = c1;
        p += fmaxf(h1, 0.f) * dw[u];
      }
      p += __shfl_xor(p, 1);
      p += __shfl_xor(p, 2);
      p += __shfl_xor(p, 4);
      p += __shfl_xor(p, 8);
      if (l15 == 0) part[wc][bl] = p;
    }
  __syncthreads();
  if (tid < 128) {
    float s = part[0][tid] + part[1][tid] + part[2][tid] + part[3][tid] +
              dec_b[0];
    out[b0 + tid] = 1.f / (1.f + __expf(-s));
  }
}

// ---------------------------------------------------------------------------
extern "C" void kernel_launch(void* const* d_in, const int* in_sizes, int n_in,
                              void* d_out, int out_size, void* d_ws,
                              size_t ws_size, hipStream_t stream) {
  const float* x = (const float*)d_in[0];
  const float* h0 = (const float*)d_in[1];
  const float* c0 = (const float*)d_in[2];
  const float* basis = (const float*)d_in[3];
  const float* w1 = (const float*)d_in[4];
  const float* b1 = (const float*)d_in[5];
  const float* w2 = (const float*)d_in[6];
  const float* b2 = (const float*)d_in[7];
  const float* w3 = (const float*)d_in[8];
  const float* b3 = (const float*)d_in[9];
  const float* w4 = (const float*)d_in[10];
  const float* b4 = (const float*)d_in[11];
  const float* w_ih = (const float*)d_in[12];
  const float* w_hh = (const float*)d_in[13];
  const float* b_ih = (const float*)d_in[14];
  const float* b_hh = (const float*)d_in[15];
  const float* dec_w = (const float*)d_in[16];
  const float* dec_b = (const float*)d_in[17];

  char* ws = (char*)d_ws;
  f16* gatesA = (f16*)(ws + OFF_GATESA);
  f16* Bf3 = (f16*)(ws + OFF_BF);
  f16* W1i = (f16*)(ws + OFF_W1);
  f16* W2 = (f16*)(ws + OFF_W2);
  f16* W3 = (f16*)(ws + OFF_W3);
  f16* W4 = (f16*)(ws + OFF_W4);
  f16* Wg = (f16*)(ws + OFF_WG);

  prep_kernel<<<256, 256, 0, stream>>>(basis, w1, w2, w3, w4, w_ih, w_hh, Bf3,
                                       W1i, W2, W3, W4, Wg);
  fused_kernel<<<2048, 1024, 0, stream>>>(x, Bf3, W1i, b1, W2, b2, W3, b3, W4,
                                          b4, gatesA);
  gates_kernel<<<256, 1024, 0, stream>>>(gatesA, h0, Wg, b_ih, b_hh, c0, dec_w,
                                         dec_b, (float*)d_out);
}

// Round 14
// 288.421 us; speedup vs baseline: 1.0311x; 1.0311x over previous
//
#include <hip/hip_runtime.h>

typedef _Float16 f16;
typedef _Float16 f16x8 __attribute__((ext_vector_type(8)));
typedef _Float16 f16x4 __attribute__((ext_vector_type(4)));
typedef float f32x4 __attribute__((ext_vector_type(4)));

#define MFMA16(a, b, c) __builtin_amdgcn_mfma_f32_16x16x32_f16((a), (b), (c), 0, 0, 0)

#define BATCH 32768

// workspace layout (bytes)
#define OFF_GATESA  ((size_t)0)                    // gatesA: B*128 f16 = 8,388,608 (dec_in only)
#define OFF_BF      (OFF_GATESA + 8388608)         // Bf3 [8][17][64][8] f16 = 139,264
#define OFF_W1      (OFF_BF + 139264)              // W1i [13][128][32] f16 = 106,496
#define OFF_W2      (OFF_W1 + 106496)              // [64][384]
#define OFF_W3      (OFF_W2 + 49152)               // [64][192]
#define OFF_W4      (OFF_W3 + 24576)               // [128][64]
#define OFF_WG      (OFF_W4 + 16384)               // [512][256]

__device__ __forceinline__ float sigmoid_(float x) { return 1.f / (1.f + __expf(-x)); }

// ---------------------------------------------------------------------------
// prep: weight repacks only. Grid 256 (R12).
// ---------------------------------------------------------------------------
__global__ __launch_bounds__(256) void prep_kernel(
    const float* __restrict__ basis, const float* __restrict__ w1,
    const float* __restrict__ w2, const float* __restrict__ w3,
    const float* __restrict__ w4, const float* __restrict__ w_ih,
    const float* __restrict__ w_hh, f16* __restrict__ Bf3,
    f16* __restrict__ W1i, f16* __restrict__ W2, f16* __restrict__ W3,
    f16* __restrict__ W4, f16* __restrict__ Wg) {
  int t = blockIdx.x * 256 + threadIdx.x;  // 0..65535
  // basis -> Bf3 frag-major [kb][tile][lane][8]
  for (int idx = t; idx < 8 * 17 * 512; idx += 65536) {
    int jj = idx & 7;
    int lane = (idx >> 3) & 63;
    int rest = idx >> 9;
    int tt = rest % 17, kb = rest / 17;
    int n = tt * 16 + (lane & 15);
    int k = kb * 32 + (lane >> 4) * 8 + jj;
    Bf3[idx] = (f16)((n < 258) ? basis[n * 256 + k] : 0.f);
  }
  // w1 (128,129,3) -> W1i[kb][n][kk], logical k = tap*136 + i, K=416
  for (int idx = t; idx < 13 * 128 * 32; idx += 65536) {
    int kb = idx / 4096, rest = idx - kb * 4096;
    int n = rest >> 5, kk = rest & 31;
    int k = kb * 32 + kk;
    int tap = k / 136, i = k - tap * 136;
    float v = (tap < 3 && i < 129) ? w1[(n * 129 + i) * 3 + tap] : 0.f;
    W1i[idx] = (f16)v;
  }
  // w2 (64,128,3) -> W2[n][k], k = tap*128 + i, K=384
  for (int idx = t; idx < 64 * 384; idx += 65536) {
    int n = idx / 384, k = idx - n * 384;
    int tap = k >> 7, i = k & 127;
    W2[idx] = (f16)w2[(n * 128 + i) * 3 + tap];
  }
  // w3 (64,64,3) -> W3[n][k], k = tap*64 + i, K=192
  for (int idx = t; idx < 64 * 192; idx += 65536) {
    int n = idx / 192, k = idx - n * 192;
    int tap = k >> 6, i = k & 63;
    W3[idx] = (f16)w3[(n * 64 + i) * 3 + tap];
  }
  // w4 (128,64,3), only tap=1 contributes -> W4[n][i], K=64
  for (int idx = t; idx < 128 * 64; idx += 65536) {
    int n = idx >> 6, i = idx & 63;
    W4[idx] = (f16)w4[(n * 64 + i) * 3 + 1];
  }
  // Wg[512][256] = [w_ih | w_hh]
  for (int idx = t; idx < 512 * 256; idx += 65536) {
    int n = idx >> 8, k = idx & 255;
    Wg[idx] = (f16)((k < 128) ? w_ih[n * 128 + k] : w_hh[n * 128 + (k - 128)]);
  }
}

// ---------------------------------------------------------------------------
// fused: R11/R12 structure (verified best: ~106us, VGPR 32, clean traffic,
// 82-85% occupancy). R13's bank-swizzle attempt REVERTED: conflicts didn't
// collapse (6.9M->6.4M, wrong mechanism — residual is shfl/scatter-write
// traffic, not the MFMA A-reads) and the XOR address math cost +10 VALU%.
// This decomposition is at its latency/barrier-structural floor: occupancy
// (233->106us over R5..R10), spill-elimination, and depth-2 pipelining are
// all captured; no pipe exceeds ~31%.
// ---------------------------------------------------------------------------
__global__ __launch_bounds__(1024, 8) void fused_kernel(
    const float* __restrict__ x, const f16* __restrict__ Bf3,
    const f16* __restrict__ W1i, const float* __restrict__ b1,
    const f16* __restrict__ W2, const float* __restrict__ b2,
    const f16* __restrict__ W3, const float* __restrict__ b3,
    const f16* __restrict__ W4, const float* __restrict__ b4,
    f16* __restrict__ gatesA) {
  __shared__ __align__(16) char smem[51968];
  f16* SF = (f16*)smem;
  float* imPatch = (float*)(smem + 49664);  // f32[9][64], dedicated
#define XP(bl, j) ((bl)*712 + (j))
#define E1(bl, s, c) ((bl)*648 + (s)*128 + (c))
#define E3(bl, c) ((bl)*72 + (c))
#define MG(bl, j) (11392 + (bl)*840 + (j))
#define E2(bl, s, c) (11392 + (bl)*200 + (s)*64 + (c))

  int tid = threadIdx.x;
  int lane = tid & 63, wv = tid >> 6;  // wv in 0..15
  int l15 = lane & 15, quad = lane >> 4;
  int b0 = blockIdx.x * 16;
  f32x4 zero4 = {0.f, 0.f, 0.f, 0.f};

  // ---- phase 0: build xpL[0,640) (tail [640,712) never read); zero ALL of
  //      magL (stale LDS there is multiplied by zero weights — no Inf/NaN). ----
  for (int idx = tid; idx < 16 * 160; idx += 1024) {
    int bl = idx / 160, g = idx - bl * 160;
    int b = b0 + bl;
    f16x4 o;
    if (g < 32) {
      float v0 = (g == 0) ? x[(size_t)b * 512] : 0.f;
      o = (f16x4){(f16)v0, (f16)0.f, (f16)0.f, (f16)0.f};
    } else {
      const float4 v = *(const float4*)(x + (size_t)b * 512 + 4 * g - 128);
      o = (f16x4){(f16)v.x, (f16)v.y, (f16)v.z, (f16)v.w};
    }
    *(f16x4*)&SF[XP(bl, 4 * g)] = o;
  }
  {
    f16x8 z8 = {};
    for (int idx = tid; idx < 16 * 105; idx += 1024) {  // full magL (840=105*8)
      int bl = idx / 105, g = idx - bl * 105;
      *(f16x8*)&SF[MG(bl, g * 8)] = z8;
    }
  }
  __syncthreads();

  // ---- STFT: wave (tp, mh): re-tile tp, im-tile tp+8, frames 2mh, 2mh+1. ----
  {
    int tp = wv & 7, mh = wv >> 3;
    const f16* Bl = Bf3 + lane * 8;
    int m0 = mh * 2, m1 = mh * 2 + 1;

    // tile16 pre-pass on waves 0 (frames 0,1) and 8 (frames 2,3).
    if (tp == 0) {
      f32x4 acc4[2] = {zero4, zero4};
      for (int kb = 0; kb < 8; kb++) {
        f16x8 bc4 = *(const f16x8*)(Bl + (size_t)kb * 17 * 512 + 16 * 512);
#pragma unroll
        for (int m = 0; m < 2; m++) {
          int mt = mh * 2 + m;
          f16x8 a = *(const f16x8*)&SF[XP(l15, mt * 128 + kb * 32 + quad * 8)];
          acc4[m] = MFMA16(a, bc4, acc4[m]);
        }
      }
      if (l15 < 2) {
        float* dst = imPatch + (l15 == 0 ? 7 : 8) * 64;
#pragma unroll
        for (int m = 0; m < 2; m++)
#pragma unroll
          for (int r = 0; r < 4; r++)
            dst[(mh * 2 + m) * 16 + quad * 4 + r] = acc4[m][r];
      }
    }

    f32x4 acc0[2], acc1v[2];
#pragma unroll
    for (int m = 0; m < 2; m++) {
      acc0[m] = zero4;
      acc1v[m] = zero4;
    }

    // depth-2 pipelined main loop.
    f16x8 a0 = *(const f16x8*)&SF[XP(l15, m0 * 128 + quad * 8)];
    f16x8 a1 = *(const f16x8*)&SF[XP(l15, m1 * 128 + quad * 8)];
    f16x8 b0 = *(const f16x8*)(Bl + tp * 512);
    f16x8 b1 = *(const f16x8*)(Bl + (tp + 8) * 512);
    for (int kb = 0; kb < 8; kb++) {
      f16x8 na0, na1, nb0, nb1;
      if (kb < 7) {
        const f16* Bn = Bl + (size_t)(kb + 1) * 17 * 512;
        nb0 = *(const f16x8*)(Bn + tp * 512);
        nb1 = *(const f16x8*)(Bn + (tp + 8) * 512);
        na0 = *(const f16x8*)&SF[XP(l15, m0 * 128 + (kb + 1) * 32 + quad * 8)];
        na1 = *(const f16x8*)&SF[XP(l15, m1 * 128 + (kb + 1) * 32 + quad * 8)];
      }
      acc0[0] = MFMA16(a0, b0, acc0[0]);
      acc1v[0] = MFMA16(a0, b1, acc1v[0]);
      acc0[1] = MFMA16(a1, b0, acc0[1]);
      acc1v[1] = MFMA16(a1, b1, acc1v[1]);
      if (kb < 7) { a0 = na0; a1 = na1; b0 = nb0; b1 = nb1; }
    }

    // Publish boundary columns.
    if (tp >= 1 && l15 == 0) {
#pragma unroll
      for (int m = 0; m < 2; m++)
#pragma unroll
        for (int r = 0; r < 4; r++)
          imPatch[(tp - 1) * 64 + (mh * 2 + m) * 16 + quad * 4 + r] =
              acc1v[m][r];
    }
    __syncthreads();

#pragma unroll
    for (int m = 0; m < 2; m++)
#pragma unroll
      for (int r = 0; r < 4; r++) {
        int mt = mh * 2 + m;
        int bl = quad * 4 + r;  // batch
        int orow = MG(bl, (mt + 1) * 136);
        int row = mt * 16 + quad * 4 + r;
        {
          float re = acc0[m][r];
          float imA = __shfl(acc1v[m][r], (quad << 4) | ((l15 + 1) & 15), 64);
          float im = (l15 == 15) ? imPatch[tp * 64 + row] : imA;
          SF[orow + 16 * tp + l15] = (f16)sqrtf(re * re + im * im);
        }
        if (tp == 0 && l15 == 0) {
          float re8 = acc1v[m][r];
          float im8 = imPatch[8 * 64 + row];
          SF[orow + 128] = (f16)sqrtf(re8 * re8 + im8 * im8);
        }
      }
  }
  __syncthreads();

  // ---- conv1: wave (nt=wv&7, ph=wv>>3), depth-2 pipelined. ----
  {
    f16x8 z8 = {};
    for (int idx = tid; idx < 16 * 16; idx += 1024) {
      int bl = idx >> 4, g = idx & 15;
      *(f16x8*)&SF[E1(bl, 0, g * 8)] = z8;  // zero e1 slot0
    }
    int nt = wv & 7, ph = wv >> 3;
    int p0 = ph * 2, p1 = ph * 2 + 1;
    f32x4 acc1[2] = {zero4, zero4};
    const f16* bbase = W1i + (nt * 16 + l15) * 32 + quad * 8;
    f16x8 b = *(const f16x8*)(bbase);
    f16x8 a0 = *(const f16x8*)&SF[MG(l15, p0 * 136 + quad * 8)];
    f16x8 a1 = *(const f16x8*)&SF[MG(l15, p1 * 136 + quad * 8)];
    for (int kb = 0; kb < 13; kb++) {
      f16x8 nb, na0, na1;
      if (kb < 12) {
        nb = *(const f16x8*)(bbase + (kb + 1) * 4096);
        na0 = *(const f16x8*)&SF[MG(l15, p0 * 136 + (kb + 1) * 32 + quad * 8)];
        na1 = *(const f16x8*)&SF[MG(l15, p1 * 136 + (kb + 1) * 32 + quad * 8)];
      }
      acc1[0] = MFMA16(a0, b, acc1[0]);
      acc1[1] = MFMA16(a1, b, acc1[1]);
      if (kb < 12) { a0 = na0; a1 = na1; b = nb; }
    }
    float bias = b1[nt * 16 + l15];
#pragma unroll
    for (int pi = 0; pi < 2; pi++)
#pragma unroll
      for (int r = 0; r < 4; r++) {
        int bl = quad * 4 + r;
        SF[E1(bl, ph * 2 + pi + 1, nt * 16 + l15)] =
            (f16)fmaxf(acc1[pi][r] + bias, 0.f);
      }
  }
  __syncthreads();

  // ---- conv2: waves 0-7, depth-2 pipelined. ----
  {
    {
      f16x8 z8 = {};
      for (int idx = tid; idx < 16 * 8; idx += 1024) {  // zero e2 slot0
        int bl = idx >> 3, g = idx & 7;
        *(f16x8*)&SF[E2(bl, 0, g * 8)] = z8;
      }
    }
    if (wv < 8) {
      int wr = wv & 1, wc = wv >> 1;
      f32x4 acc2 = zero4;
      const f16* bbase = W2 + (size_t)(wc * 16 + l15) * 384 + quad * 8;
      f16x8 b = *(const f16x8*)(bbase);
      f16x8 a = *(const f16x8*)&SF[E1(l15, wr * 2, quad * 8)];
      for (int kb = 0; kb < 12; kb++) {
        f16x8 nb, na;
        if (kb < 11) {
          nb = *(const f16x8*)(bbase + (kb + 1) * 32);
          na = *(const f16x8*)&SF[E1(l15, wr * 2, (kb + 1) * 32 + quad * 8)];
        }
        acc2 = MFMA16(a, b, acc2);
        if (kb < 11) { a = na; b = nb; }
      }
      float bias = b2[wc * 16 + l15];
#pragma unroll
      for (int r = 0; r < 4; r++) {
        int bl = quad * 4 + r;
        SF[E2(bl, wr + 1, wc * 16 + l15)] = (f16)fmaxf(acc2[r] + bias, 0.f);
      }
    }
  }
  __syncthreads();

  // ---- conv3: waves 0-3. ----
  if (wv < 4) {
    f32x4 acc3 = zero4;
    const f16* bbase = W3 + (size_t)(wv * 16 + l15) * 192 + quad * 8;
    for (int kb = 0; kb < 6; kb++) {
      f16x8 a = *(const f16x8*)&SF[E2(l15, 0, kb * 32 + quad * 8)];
      f16x8 bf = *(const f16x8*)(bbase + kb * 32);
      acc3 = MFMA16(a, bf, acc3);
    }
    float bias = b3[wv * 16 + l15];
#pragma unroll
    for (int r = 0; r < 4; r++) {
      int bl = quad * 4 + r;
      SF[E3(bl, wv * 16 + l15)] = (f16)fmaxf(acc3[r] + bias, 0.f);
    }
  }
  __syncthreads();

  // ---- conv4: waves 0-7 -> gatesA [B][128] ----
  if (wv < 8) {
    f32x4 acc4a = zero4;
    const f16* bbase = W4 + (size_t)(wv * 16 + l15) * 64 + quad * 8;
    for (int kb = 0; kb < 2; kb++) {
      f16x8 a = *(const f16x8*)&SF[E3(l15, kb * 32 + quad * 8)];
      f16x8 bf0 = *(const f16x8*)(bbase + kb * 32);
      acc4a = MFMA16(a, bf0, acc4a);
    }
    float bias = b4[wv * 16 + l15];
#pragma unroll
    for (int r = 0; r < 4; r++) {
      int bl = quad * 4 + r;
      gatesA[(size_t)(b0 + bl) * 128 + wv * 16 + l15] =
          (f16)fmaxf(acc4a[r] + bias, 0.f);
    }
  }
#undef XP
#undef MG
#undef E1
#undef E2
#undef E3
}

// ---------------------------------------------------------------------------
// gates GEMM + LSTM cell + decision head. M=128/block, 256 blocks, 1024
// threads / 16 waves (R12). A = [dec_in (f16) | h0 (f32 in-reg)], K=256.
// ---------------------------------------------------------------------------
__global__ __launch_bounds__(1024, 2) void gates_kernel(
    const f16* __restrict__ gatesA, const float* __restrict__ h0,
    const f16* __restrict__ Wg, const float* __restrict__ b_ih,
    const float* __restrict__ b_hh, const float* __restrict__ c0,
    const float* __restrict__ dec_w, const float* __restrict__ dec_b,
    float* __restrict__ out) {
  __shared__ float part[4][128];
  int tid = threadIdx.x;
  int lane = tid & 63, wv = tid >> 6;  // 0..15
  int wc = wv & 3;                     // col-group: cols wc*32 + u*16 + l15
  int wm = wv >> 2;                    // m-pair: mt = wm*2 + m, mt in 0..7
  int l15 = lane & 15, quad = lane >> 4;
  int b0 = blockIdx.x * 128;
  f32x4 zero4 = {0.f, 0.f, 0.f, 0.f};

  float* out_h1 = out + BATCH;
  float* out_c1 = out + BATCH + (size_t)BATCH * 128;

  f32x4 acc[2][8];  // [m][q*2+u]
#pragma unroll
  for (int m = 0; m < 2; m++)
#pragma unroll
    for (int j = 0; j < 8; j++) acc[m][j] = zero4;

  const f16* aptr[2];
  const float* hptr[2];
#pragma unroll
  for (int m = 0; m < 2; m++) {
    int mt = wm * 2 + m;
    aptr[m] = gatesA + (size_t)(b0 + mt * 16 + l15) * 128 + quad * 8;
    hptr[m] = h0 + (size_t)(b0 + mt * 16 + l15) * 128 + quad * 8;
  }

  const f16* bptrs[8];
#pragma unroll
  for (int q = 0; q < 4; q++)
#pragma unroll
    for (int u = 0; u < 2; u++)
      bptrs[q * 2 + u] =
          Wg + (size_t)(q * 128 + wc * 32 + u * 16 + l15) * 256 + quad * 8;

#pragma unroll
  for (int k0 = 0; k0 < 256; k0 += 32) {
    f16x8 a[2];
    if (k0 < 128) {
#pragma unroll
      for (int m = 0; m < 2; m++) a[m] = *(const f16x8*)(aptr[m] + k0);
    } else {
#pragma unroll
      for (int m = 0; m < 2; m++) {
        const float* hp = hptr[m] + (k0 - 128);
        float4 v0 = *(const float4*)hp;
        float4 v1 = *(const float4*)(hp + 4);
        a[m] = (f16x8){(f16)v0.x, (f16)v0.y, (f16)v0.z, (f16)v0.w,
                       (f16)v1.x, (f16)v1.y, (f16)v1.z, (f16)v1.w};
      }
    }
#pragma unroll
    for (int j = 0; j < 8; j++) {
      f16x8 bf = *(const f16x8*)(bptrs[j] + k0);
#pragma unroll
      for (int m = 0; m < 2; m++) acc[m][j] = MFMA16(a[m], bf, acc[m][j]);
    }
  }

  float bias[8], dw[2];
#pragma unroll
  for (int q = 0; q < 4; q++)
#pragma unroll
    for (int u = 0; u < 2; u++) {
      int n = q * 128 + wc * 32 + u * 16 + l15;
      bias[q * 2 + u] = b_ih[n] + b_hh[n];
    }
#pragma unroll
  for (int u = 0; u < 2; u++) dw[u] = dec_w[wc * 32 + u * 16 + l15];

#pragma unroll
  for (int m = 0; m < 2; m++)
#pragma unroll
    for (int r = 0; r < 4; r++) {
      int bl = (wm * 2 + m) * 16 + quad * 4 + r;
      int b = b0 + bl;
      float p = 0.f;
#pragma unroll
      for (int u = 0; u < 2; u++) {
        int c = wc * 32 + u * 16 + l15;
        float iv = acc[m][0 + u][r] + bias[0 + u];
        float fv = acc[m][2 + u][r] + bias[2 + u];
        float gv = acc[m][4 + u][r] + bias[4 + u];
        float ov = acc[m][6 + u][r] + bias[6 + u];
        float c0v = c0[(size_t)b * 128 + c];
        float c1 = sigmoid_(fv) * c0v + sigmoid_(iv) * tanhf(gv);
        float h1 = sigmoid_(ov) * tanhf(c1);
        out_h1[(size_t)b * 128 + c] = h1;
        out_c1[(size_t)b * 128 + c] = c1;
        p += fmaxf(h1, 0.f) * dw[u];
      }
      p += __shfl_xor(p, 1);
      p += __shfl_xor(p, 2);
      p += __shfl_xor(p, 4);
      p += __shfl_xor(p, 8);
      if (l15 == 0) part[wc][bl] = p;
    }
  __syncthreads();
  if (tid < 128) {
    float s = part[0][tid] + part[1][tid] + part[2][tid] + part[3][tid] +
              dec_b[0];
    out[b0 + tid] = 1.f / (1.f + __expf(-s));
  }
}

// ---------------------------------------------------------------------------
extern "C" void kernel_launch(void* const* d_in, const int* in_sizes, int n_in,
                              void* d_out, int out_size, void* d_ws,
                              size_t ws_size, hipStream_t stream) {
  const float* x = (const float*)d_in[0];
  const float* h0 = (const float*)d_in[1];
  const float* c0 = (const float*)d_in[2];
  const float* basis = (const float*)d_in[3];
  const float* w1 = (const float*)d_in[4];
  const float* b1 = (const float*)d_in[5];
  const float* w2 = (const float*)d_in[6];
  const float* b2 = (const float*)d_in[7];
  const float* w3 = (const float*)d_in[8];
  const float* b3 = (const float*)d_in[9];
  const float* w4 = (const float*)d_in[10];
  const float* b4 = (const float*)d_in[11];
  const float* w_ih = (const float*)d_in[12];
  const float* w_hh = (const float*)d_in[13];
  const float* b_ih = (const float*)d_in[14];
  const float* b_hh = (const float*)d_in[15];
  const float* dec_w = (const float*)d_in[16];
  const float* dec_b = (const float*)d_in[17];

  char* ws = (char*)d_ws;
  f16* gatesA = (f16*)(ws + OFF_GATESA);
  f16* Bf3 = (f16*)(ws + OFF_BF);
  f16* W1i = (f16*)(ws + OFF_W1);
  f16* W2 = (f16*)(ws + OFF_W2);
  f16* W3 = (f16*)(ws + OFF_W3);
  f16* W4 = (f16*)(ws + OFF_W4);
  f16* Wg = (f16*)(ws + OFF_WG);

  prep_kernel<<<256, 256, 0, stream>>>(basis, w1, w2, w3, w4, w_ih, w_hh, Bf3,
                                       W1i, W2, W3, W4, Wg);
  fused_kernel<<<2048, 1024, 0, stream>>>(x, Bf3, W1i, b1, W2, b2, W3, b3, W4,
                                          b4, gatesA);
  gates_kernel<<<256, 1024, 0, stream>>>(gatesA, h0, Wg, b_ih, b_hh, c0, dec_w,
                                         dec_b, (float*)d_out);
}